// Round 3
// 206.725 us; speedup vs baseline: 1.0144x; 1.0144x over previous
//
#include <hip/hip_runtime.h>

// Problem constants (from reference setup_inputs):
//   x:        [B=16, Cin=128, N=8192] fp32
//   weights1: [Cin=128, Cout=128, modes1=2048] fp32
//   out:      [B=16, Cout=128, L=4097] fp32
//
// Math collapse (verified earlier, absmax 0.0): the recursive "RFHT" of a
// power-of-two-length row is [rowsum, 0, ..., 0]; the neg()-mixing collapses
// to a plain channel matmul on mode 0; the inverse transform of an impulse
// at 0 over odd length 4097 is again an impulse at 0.
// => out[b,o,n] = delta(n==0) * (1/4097) * sum_i (sum_n x[b,i,n]) * w[i,o,0]
//
// R5 = R3 with the nontemporal builtins fixed: __builtin_nontemporal_* needs
// a NATIVE vector type (ext_vector_type), not HIP's float4 class.
// R3 change (split pure-read / pure-write streams):
//   k1: row sums only — 64 MB unidirectional READ (no store traffic mixed in).
//   k2: one block per output row (b,o) — zeros elems 1..4096 and writes the
//       mix value at elem 0. Pure 33.5 MB WRITE stream; the 8KB-strided
//       w-gather latency hides under the zero stores. Row ownership per block
//       removes any cross-block zero-vs-value ordering hazard.

#define NN    8192
#define BB    16
#define CIN   128
#define COUT  128
#define MODES 2048
#define LOUT  4097

#define ROWS     (BB * CIN)   // 2048 x-rows
#define THREADS1 256

typedef float f4 __attribute__((ext_vector_type(4)));   // native vector: OK for nontemporal builtins

// Kernel 1: S[r] = sum of x-row r (pure read, 64 MB total).
__global__ __launch_bounds__(256) void sum_kernel(const float* __restrict__ x,
                                                  float* __restrict__ S) {
    const int t = threadIdx.x;
    const int r = blockIdx.x;
    const f4* __restrict__ xp = (const f4*)(x + (size_t)r * NN);

    f4 v[8];
#pragma unroll
    for (int it = 0; it < 8; ++it)
        v[it] = __builtin_nontemporal_load(&xp[t + it * THREADS1]);

    float acc = 0.f;
#pragma unroll
    for (int it = 0; it < 8; ++it)
        acc += (v[it].x + v[it].y) + (v[it].z + v[it].w);

#pragma unroll
    for (int off = 32; off > 0; off >>= 1)
        acc += __shfl_down(acc, off, 64);
    __shared__ float wsum[4];
    const int lane = t & 63, wid = t >> 6;
    if (lane == 0) wsum[wid] = acc;
    __syncthreads();
    if (t == 0) S[r] = (wsum[0] + wsum[1]) + (wsum[2] + wsum[3]);
}

// Kernel 2: block bo = b*128+o owns output row [b,o,:]:
//   zeros elems 1..4096, writes (1/4097)*sum_i S[b,i]*w[i,o,0] at elem 0.
// Rows are only 4-byte aligned (4097 floats), so scalar head/tail + aligned
// f4 body for the zero fill.
__global__ __launch_bounds__(256) void zero_mix_kernel(const float* __restrict__ S,
                                                       const float* __restrict__ w,
                                                       float* __restrict__ out) {
    const int bo = blockIdx.x;
    const int b = bo >> 7, o = bo & 127;
    const int t = threadIdx.x;

    // Mix partial product (threads 0..127, one input channel each).
    float p = 0.f;
    if (t < CIN)
        p = S[b * CIN + t] * w[((size_t)t * COUT + o) * MODES];

    // Zero range: global float indices [g0, g1) = row elems 1..4096.
    const size_t g0 = (size_t)bo * LOUT + 1;
    const size_t g1 = (size_t)(bo + 1) * LOUT;
    const size_t a0 = (g0 + 3) & ~(size_t)3;   // first 16B-aligned index
    const size_t a1 = g1 & ~(size_t)3;         // last aligned (exclusive)

    if (t < 4) {
        size_t g = g0 + t;                      // scalar head (<=3 elems)
        if (g < a0) __builtin_nontemporal_store(0.f, &out[g]);
        g = a1 + t;                             // scalar tail (<=3 elems)
        if (g < g1) __builtin_nontemporal_store(0.f, &out[g]);
    }
    const f4 z = (f4)(0.f);
    f4* o4 = (f4*)out;
    for (size_t f = a0 / 4 + t; f < a1 / 4; f += 256)
        __builtin_nontemporal_store(z, &o4[f]);

    // Reduce p across threads 0..127 (two waves), write row elem 0.
#pragma unroll
    for (int off = 32; off > 0; off >>= 1)
        p += __shfl_down(p, off, 64);
    __shared__ float ws2[2];
    if (t == 0) ws2[0] = p;
    if (t == 64) ws2[1] = p;
    __syncthreads();
    if (t == 0)
        out[(size_t)bo * LOUT] = (ws2[0] + ws2[1]) * (1.0f / (float)LOUT);
}

extern "C" void kernel_launch(void* const* d_in, const int* in_sizes, int n_in,
                              void* d_out, int out_size, void* d_ws, size_t ws_size,
                              hipStream_t stream) {
    const float* x = (const float*)d_in[0];   // 16*128*8192
    const float* w = (const float*)d_in[1];   // 128*128*2048
    float* out = (float*)d_out;               // 16*128*4097
    float* S = (float*)d_ws;                  // 2048 floats of scratch

    sum_kernel<<<ROWS, THREADS1, 0, stream>>>(x, S);
    zero_mix_kernel<<<BB * COUT, THREADS1, 0, stream>>>(S, w, out);
}